// Round 8
// baseline (262.719 us; speedup 1.0000x reference)
//
#include <hip/hip_runtime.h>

#define NQ     14
#define NL     4
#define BATCH  2048
#define DIM    16384
#define BLK    512

using f2 = __attribute__((ext_vector_type(2))) float;

__device__ __forceinline__ f2 swapf2(f2 v) { return __builtin_shufflevector(v, v, 1, 0); }

// Parity-form storage: amp a held as (x,y) if popc(a) even, (y,x) if odd.
// RX on register-index bit B: pairs have opposite amp-parity; update is pure
// elementwise packed math (no swaps in the IR):
//   st_even' = C*st_even + S*st_odd ;  st_odd' = C*st_odd - S*st_even
// with C=(c,c), S=(s,-s). Per-pair sign = thread-parity (folded into Sp/Sm)
// XOR compile-time parity(j_lo).
template <int B>
__device__ __forceinline__ void rot_bit(f2* v, f2 C, f2 Sp, f2 Sm) {
#pragma unroll
  for (int j = 0; j < 32; ++j) {
    if (!(j & B)) {
      const int j1 = j | B;
      const bool parj = __builtin_popcount((unsigned)j) & 1;  // compile-time after unroll
      const f2 SL = parj ? Sm : Sp;
      const f2 SR = parj ? Sp : Sm;
      const f2 a0 = v[j], a1 = v[j1];
      v[j]  = __builtin_elementwise_fma(C, a0, SL * a1);
      v[j1] = __builtin_elementwise_fma(C, a1, SR * a0);
    }
  }
}

// CNOT-ring basis map (linear over GF(2)): jf(k) = (y & 0x1FFF) | ((y0^k13)<<13), y=suffix-xor(k)
__device__ __forceinline__ int cnot_map(int k) {
  int y = k; y ^= y >> 1; y ^= y >> 2; y ^= y >> 4; y ^= y >> 8;
  return (y & 0x1FFF) | (((y ^ (k >> 13)) & 1) << 13);
}
// compile-time images of amp-bits 9..13 under the CNOT map
__host__ __device__ constexpr int G_of(int j) {
  int g = 0;
  if (j & 1)  g ^= 0x23FF;  // M(e9)
  if (j & 2)  g ^= 0x27FF;  // M(e10)
  if (j & 4)  g ^= 0x2FFF;  // M(e11)
  if (j & 8)  g ^= 0x3FFF;  // M(e12)
  if (j & 16) g ^= 0x1FFF;  // M(e13)
  return g;
}

__global__ __launch_bounds__(BLK, 2) void qsim_kernel(const float* __restrict__ x,
                                                      const float* __restrict__ params,
                                                      float* __restrict__ out) {
  // fixed layout: logical chunk c (amps 2c,2c+1) at physical chunk c + (c>>4)
  __shared__ float4 lds4[DIM / 2 + DIM / 32];  // 8704 chunks = 139264 B
  __shared__ float exc[NQ], exs[NQ];
  __shared__ float gc[NL * NQ], gs[NL * NQ];
  __shared__ float red[8][16];
  f2* lds2 = reinterpret_cast<f2*>(lds4);      // f2 slot s -> phys s + 2*(s>>5)

  const int b = blockIdx.x;
  const int t = threadIdx.x;

  if (t < NQ)      { const float xv = x[b * NQ + t]; exc[t] = cosf(0.5f * xv); exs[t] = sinf(0.5f * xv); }
  if (t < NL * NQ) { const float th = 0.5f * params[t]; gc[t] = cosf(th); gs[t] = sinf(th); }
  __syncthreads();

  float4 tile[16];
  f2* v = reinterpret_cast<f2*>(tile);

  const int Pt = __popc(t) & 1;                // thread amp-parity contribution

  // ---- embedding in pass-A ownership: amp a = (t<<5)|j.
  // True amp = (-i)^pc * f. In parity-form storage this is ALWAYS (±f, 0):
  // pc∈{0,3} -> +f ; pc∈{1,2} -> -f.
  {
    float pb = 1.0f;
#pragma unroll
    for (int pt = 0; pt < 9; ++pt) pb *= ((t >> pt) & 1) ? exs[8 - pt] : exc[8 - pt];
    const int pct = __popc(t);
#pragma unroll
    for (int j = 0; j < 32; ++j) {
      float f = pb;
#pragma unroll
      for (int bb = 0; bb < 5; ++bb) f *= ((j >> bb) & 1) ? exs[13 - bb] : exc[13 - bb];
      const int pc = (pct + __popc(j)) & 3;
      f2 av;
      av.x = (pc == 0 || pc == 3) ? f : -f;
      av.y = 0.0f;
      v[j] = av;
    }
  }

  const int baseA = 17 * t;                    // phys chunk of c=16t (pass A, self-owned)
  const int baseB = (t & 15) + 272 * (t >> 4); // phys chunk; offsets 17*jj (intra-wave group)
  const int baseC = t + 2 * (t >> 5);          // phys f2 slot; offsets 544*j
  const int jft   = cnot_map(t);

  // CNOT scatter byte-offsets are layer-invariant: precompute once
  int soff[32];
#pragma unroll
  for (int j = 0; j < 32; ++j) {
    const int s = jft ^ G_of(j);
    soff[j] = (s + 2 * (s >> 5)) * 8;          // pad-swizzled f2 slot, in bytes
  }
  char* const sbase = (char*)lds2;
  // parity-form flip under CNOT: popc(M(a))^popc(a) = parity(a & 0x1555);
  // a = t|(j<<9) -> flip = parity(t&0x155) ^ parity(j&0xA)
  const int Pscat = __popc(t & 0x155) & 1;

#pragma unroll
  for (int layer = 0; layer < NL; ++layer) {   // fully unrolled: immediate lc/ls offsets
    const float* lc = gc + layer * NQ;
    const float* ls = gs + layer * NQ;

    f2 C, Sp, Sm;
#define MKCS(qi)                                            \
    { const float c_ = lc[qi], s_ = ls[qi];                 \
      const float sq_ = Pt ? -s_ : s_;                      \
      C.x = c_; C.y = c_;                                   \
      Sp.x = sq_; Sp.y = -sq_;                              \
      Sm.x = -sq_; Sm.y = sq_; }

    // ---- pass A: own amps a=(t<<5)|j ; rotate q13..q9 (reg bits 0..4). Self-owned slots.
    if (layer > 0) {
#pragma unroll
      for (int i = 0; i < 16; ++i) tile[i] = lds4[baseA + i];
    }
    MKCS(13); rot_bit<1>(v, C, Sp, Sm);
    MKCS(12); rot_bit<2>(v, C, Sp, Sm);
    MKCS(11); rot_bit<4>(v, C, Sp, Sm);
    MKCS(10); rot_bit<8>(v, C, Sp, Sm);
    MKCS(9);  rot_bit<16>(v, C, Sp, Sm);
#pragma unroll
    for (int i = 0; i < 16; ++i) lds4[baseA + i] = tile[i];

    // A->B exchange is wave-private (B sources vary only A-lane bits 0..3):
    // in-order per-wave DS pipe makes data visible; fence the compiler only.
    __builtin_amdgcn_wave_barrier();

    // ---- pass B: free amp-bits {0,5,6,7,8}; rotate q8..q5 (reg bits 1..4)
#pragma unroll
    for (int jj = 0; jj < 16; ++jj) tile[jj] = lds4[baseB + 17 * jj];
    MKCS(8); rot_bit<2>(v, C, Sp, Sm);
    MKCS(7); rot_bit<4>(v, C, Sp, Sm);
    MKCS(6); rot_bit<8>(v, C, Sp, Sm);
    MKCS(5); rot_bit<16>(v, C, Sp, Sm);
#pragma unroll
    for (int jj = 0; jj < 16; ++jj) lds4[baseB + 17 * jj] = tile[jj];
    __syncthreads();                           // B->C repartition crosses waves

    // ---- pass C: own amps a = t | (j<<9); rotate q4..q0 (reg bits 0..4)
#pragma unroll
    for (int j = 0; j < 16; ++j) v[j] = lds2[baseC + 544 * j];
#pragma unroll
    for (int j = 16; j < 32; ++j) v[j] = lds2[(baseC + 16 * 544) + 544 * (j - 16)];
    MKCS(4); rot_bit<1>(v, C, Sp, Sm);
    MKCS(3); rot_bit<2>(v, C, Sp, Sm);
    MKCS(2); rot_bit<4>(v, C, Sp, Sm);
    MKCS(1); rot_bit<8>(v, C, Sp, Sm);
    MKCS(0); rot_bit<16>(v, C, Sp, Sm);
#undef MKCS

    if (layer < NL - 1) {
      __syncthreads();                         // WAR: all pass-C reads done
#pragma unroll
      for (int j = 0; j < 32; ++j) {           // CNOT fold + parity-form fixup
        const bool flip = ((__popc((unsigned)(j & 0xA)) & 1) ? !Pscat : Pscat) != 0;
        const f2 w = flip ? swapf2(v[j]) : v[j];
        *(f2*)(sbase + soff[j]) = w;
      }
      __syncthreads();                         // RAW for next layer's pass-A read
    }
  }

  // ---- measurement: final CNOT folded via GF(2)-linearity. |amp|^2 is
  // parity-form invariant. reg-WHT then lane-Walsh butterflies.
  {
    float p[32];
#pragma unroll
    for (int j = 0; j < 32; ++j) p[j] = v[j].x * v[j].x + v[j].y * v[j].y;
#pragma unroll
    for (int st = 0; st < 5; ++st) {
      const int h = 1 << st;
#pragma unroll
      for (int j = 0; j < 32; ++j) {
        if (!(j & h)) {
          const float u = p[j], w = p[j | h];
          p[j] = u + w;
          p[j | h] = u - w;
        }
      }
    }
    float a31 = p[31], a15 = p[15], a24 = p[24], a28 = p[28], a30 = p[30];
    const int lane = t & 63;
#pragma unroll
    for (int m = 0; m < 6; ++m) {
      const int h = 1 << m;
      const bool hi = (lane & h) != 0;
      float u;
      u = __shfl_xor(a31, h, 64); a31 = hi ? (u - a31) : (u + a31);
      u = __shfl_xor(a15, h, 64); a15 = hi ? (u - a15) : (u + a15);
      u = __shfl_xor(a24, h, 64); a24 = u + a24;   // plain sums: only lane 0 used
      u = __shfl_xor(a28, h, 64); a28 = u + a28;
      u = __shfl_xor(a30, h, 64); a30 = u + a30;
    }
    const int w = t >> 6;
    const float sw = (__popc(w) & 1) ? -1.0f : 1.0f;
    if (lane == 0) {
      red[w][1] = a24;                          // q1..q4: sign +1 (jft bits 9..12 = 0)
      red[w][2] = a28;
      red[w][3] = a30;
      red[w][4] = a31;
      red[w][5] = (w & 4) ? -a31 : a31;         // q5: (-1)^t8
      red[w][6] = (((w >> 1) ^ (w >> 2)) & 1) ? -a31 : a31;  // q6: (-1)^(t7^t8)
      red[w][7] = sw * a31;                     // q7: (-1)^(t6^t7^t8)
    } else if (lane == 32) { red[w][8]  = sw * a31; }   // q8:  mask 0x20
    else if (lane == 48)   { red[w][9]  = sw * a31; }   // q9:  mask 0x30
    else if (lane == 56)   { red[w][10] = sw * a31; }   // q10: mask 0x38
    else if (lane == 60)   { red[w][11] = sw * a31; }   // q11: mask 0x3C
    else if (lane == 62)   { red[w][12] = sw * a31; }   // q12: mask 0x3E
    else if (lane == 63)   { red[w][13] = sw * a31;     // q13: mask 0x3F
                             red[w][0]  = sw * a15; }   // q0:  mask 0x3F on p15
    __syncthreads();
    if (t < NQ) {
      float sq = 0.0f;
#pragma unroll
      for (int ww = 0; ww < 8; ++ww) sq += red[ww][t];
      out[b * NQ + t] = sq;
    }
  }
}

extern "C" void kernel_launch(void* const* d_in, const int* in_sizes, int n_in,
                              void* d_out, int out_size, void* d_ws, size_t ws_size,
                              hipStream_t stream) {
  const float* x      = (const float*)d_in[0];
  const float* params = (const float*)d_in[1];
  float* out          = (float*)d_out;
  qsim_kernel<<<BATCH, BLK, 0, stream>>>(x, params, out);
}

// Round 9
// 234.539 us; speedup vs baseline: 1.1202x; 1.1202x over previous
//
#include <hip/hip_runtime.h>
#include <hip/hip_fp16.h>

#define NQ     14
#define NL     4
#define BATCH  2048
#define DIM    16384
#define BLK    512
#define NCH    (DIM / 4)            // 4096 logical uint4 chunks (4 amps each, fp16x2)
#define PCH    (NCH + NCH / 8)      // 4608 physical chunks (pad c + c>>3)

using f2 = __attribute__((ext_vector_type(2))) float;

__device__ __forceinline__ f2 swapf2(f2 v) { return __builtin_shufflevector(v, v, 1, 0); }

// RX on register-index bit B of a 32-amp (f2) tile (storage plain re/im).
template <int B>
__device__ __forceinline__ void rot_bit(f2* v, float c, float s) {
  const f2 C = {c, c};
  const f2 S = {s, -s};
#pragma unroll
  for (int j = 0; j < 32; ++j) {
    if (!(j & B)) {
      const int j1 = j | B;
      const f2 a0 = v[j], a1 = v[j1];
      v[j]  = __builtin_elementwise_fma(C, a0, S * swapf2(a1));
      v[j1] = __builtin_elementwise_fma(C, a1, S * swapf2(a0));
    }
  }
}

// fp16x2 <-> f2 (RN rounding: RTZ's systematic shrink would bias Z by ~1e-2)
__device__ __forceinline__ f2 up2(unsigned u) {
  const __half2 h = __builtin_bit_cast(__half2, u);
  f2 r; r.x = __low2float(h); r.y = __high2float(h); return r;
}
__device__ __forceinline__ unsigned dn2(f2 v) {
  return __builtin_bit_cast(unsigned, __floats2half2_rn(v.x, v.y));
}

__global__ __launch_bounds__(BLK, 4) void qsim_kernel(const float* __restrict__ x,
                                                      const float* __restrict__ params,
                                                      float* __restrict__ out) {
  __shared__ uint4 lds[PCH];                  // 73728 B state, fp16-packed, padded
  __shared__ float exc[NQ], exs[NQ];
  __shared__ float gc[NL * NQ], gs[NL * NQ];
  __shared__ float red[8][16];
  char* const sb = (char*)lds;

  const int b = blockIdx.x;
  const int t = threadIdx.x;

  if (t < NQ)      { const float xv = x[b * NQ + t]; exc[t] = cosf(0.5f * xv); exs[t] = sinf(0.5f * xv); }
  if (t < NL * NQ) { const float th = 0.5f * params[t]; gc[t] = cosf(th); gs[t] = sinf(th); }
  __syncthreads();

  f2 v[32];

  // ---- per-thread bases (phys chunk = c + (c>>3); all layer-invariant)
  // A: own amps 32t+j, chunks 8t+i -> phys 9t+i
  char* const pA = sb + 16 * (9 * t);
  // B: free amp bits {0,1,5,6,7}; chunk c = (t&7) + 8m + 64(t>>3) -> phys (t&7)+9m+72(t>>3)
  char* const pB = sb + 16 * (t & 7) + 1152 * (t >> 3);
  // C: free {0,1,8,9,10}; c = (t&63) + 64m + 512(t>>6) -> phys +((t>>3)&7) + 72m + 576(t>>6)
  char* const pC = sb + 16 * ((t & 63) + ((t >> 3) & 7) + 576 * (t >> 6));
  // D: free {0,1,11,12,13}; c = t + 512m -> phys t + (t>>3) + 576m
  char* const pD = sb + 16 * (t + (t >> 3));

  // D CNOT-fold: target chunk for group g = (MA0 ^ Mrep(g))>>2, images of amp bits 2..10
  int MA0 = 0;
  {
    const int Me[9] = {0x2007, 0x200F, 0x201F, 0x203F, 0x207F, 0x20FF, 0x21FF, 0x23FF, 0x27FF};
#pragma unroll
    for (int i = 0; i < 9; ++i) if ((t >> i) & 1) MA0 ^= Me[i];
  }
  int offD[8];
#pragma unroll
  for (int g = 0; g < 8; ++g) {
    const int Mrep = ((g & 1) ? 0x2FFF : 0) ^ ((g & 2) ? 0x3FFF : 0) ^ ((g & 4) ? 0x1FFF : 0);
    const int cT = (MA0 ^ Mrep) >> 2;
    offD[g] = 16 * (cT + (cT >> 3));
  }
  const int P = __popc(t) & 1;                // both low parities of A0 = t<<2 equal popc(t)

  // ---- embedding in pass-A ownership: amp a = 32t + 4i + l; amp bit p <-> qubit 13-p
  {
    float pb = 1.0f;
#pragma unroll
    for (int p = 0; p < 9; ++p) pb *= ((t >> p) & 1) ? exs[8 - p] : exc[8 - p];
    const int pct = __popc(t);
#pragma unroll
    for (int i = 0; i < 8; ++i) {
      const float fc = ((i & 1) ? exs[11] : exc[11]) * ((i & 2) ? exs[10] : exc[10]) *
                       ((i & 4) ? exs[9] : exc[9]);
#pragma unroll
      for (int l = 0; l < 4; ++l) {
        const float fl = ((l & 1) ? exs[13] : exc[13]) * ((l & 2) ? exs[12] : exc[12]);
        const float f = pb * fc * fl;
        const int pc = (pct + __popc(i) + __popc(l)) & 3;
        f2 av;
        av.x = (pc == 0) ? f : ((pc == 2) ? -f : 0.0f);
        av.y = (pc == 1) ? -f : ((pc == 3) ? f : 0.0f);
        v[4 * i + l] = av;
      }
    }
  }

#pragma unroll
  for (int layer = 0; layer < NL; ++layer) {
    const float* lc = gc + layer * NQ;
    const float* ls = gs + layer * NQ;

    // ---- pass A: rotate q13..q9 (reg bits 0..4); self-owned contiguous chunks
    if (layer > 0) {
#pragma unroll
      for (int i = 0; i < 8; ++i) {
        const uint4 u = *(const uint4*)(pA + 16 * i);
        v[4 * i] = up2(u.x); v[4 * i + 1] = up2(u.y); v[4 * i + 2] = up2(u.z); v[4 * i + 3] = up2(u.w);
      }
    }
    rot_bit<1>(v, lc[13], ls[13]);
    rot_bit<2>(v, lc[12], ls[12]);
    rot_bit<4>(v, lc[11], ls[11]);
    rot_bit<8>(v, lc[10], ls[10]);
    rot_bit<16>(v, lc[9], ls[9]);
#pragma unroll
    for (int i = 0; i < 8; ++i)
      *(uint4*)(pA + 16 * i) = make_uint4(dn2(v[4 * i]), dn2(v[4 * i + 1]), dn2(v[4 * i + 2]), dn2(v[4 * i + 3]));
    // A->B exchange is wave-private (both roles' wave = amp bits 11..13)
    __builtin_amdgcn_wave_barrier();

    // ---- pass B: free {0,1,5,6,7}; rotate q8,q7,q6 (reg bits 2,3,4)
#pragma unroll
    for (int m = 0; m < 8; ++m) {
      const uint4 u = *(const uint4*)(pB + 144 * m);
      v[4 * m] = up2(u.x); v[4 * m + 1] = up2(u.y); v[4 * m + 2] = up2(u.z); v[4 * m + 3] = up2(u.w);
    }
    rot_bit<4>(v, lc[8], ls[8]);
    rot_bit<8>(v, lc[7], ls[7]);
    rot_bit<16>(v, lc[6], ls[6]);
#pragma unroll
    for (int m = 0; m < 8; ++m)
      *(uint4*)(pB + 144 * m) = make_uint4(dn2(v[4 * m]), dn2(v[4 * m + 1]), dn2(v[4 * m + 2]), dn2(v[4 * m + 3]));
    // B->C exchange also wave-private
    __builtin_amdgcn_wave_barrier();

    // ---- pass C: free {0,1,8,9,10}; rotate q5,q4,q3 (reg bits 2,3,4)
#pragma unroll
    for (int m = 0; m < 8; ++m) {
      const uint4 u = *(const uint4*)(pC + 1152 * m);
      v[4 * m] = up2(u.x); v[4 * m + 1] = up2(u.y); v[4 * m + 2] = up2(u.z); v[4 * m + 3] = up2(u.w);
    }
    rot_bit<4>(v, lc[5], ls[5]);
    rot_bit<8>(v, lc[4], ls[4]);
    rot_bit<16>(v, lc[3], ls[3]);
#pragma unroll
    for (int m = 0; m < 8; ++m)
      *(uint4*)(pC + 1152 * m) = make_uint4(dn2(v[4 * m]), dn2(v[4 * m + 1]), dn2(v[4 * m + 2]), dn2(v[4 * m + 3]));
    __syncthreads();                          // C->D repartition crosses waves

    // ---- pass D: free {0,1,11,12,13}; rotate q2,q1,q0 (reg bits 2,3,4)
#pragma unroll
    for (int m = 0; m < 8; ++m) {
      const uint4 u = *(const uint4*)(pD + 9216 * m);
      v[4 * m] = up2(u.x); v[4 * m + 1] = up2(u.y); v[4 * m + 2] = up2(u.z); v[4 * m + 3] = up2(u.w);
    }
    if (layer < NL - 1) __syncthreads();      // WAR: all D reads done before CNOT writes
    rot_bit<4>(v, lc[2], ls[2]);
    rot_bit<8>(v, lc[1], ls[1]);
    rot_bit<16>(v, lc[0], ls[0]);

    if (layer < NL - 1) {
      // CNOT ring folded into full-chunk writes: group g -> chunk (MA0^Mrep)>>2.
      // Members {rep, rep^25, rep^3, rep^26} fill slots {d0, d0^1, d0^2, d0^3},
      // d0 = 3*(P^parity(g)) -> identity or full reverse.
#pragma unroll
      for (int g = 0; g < 8; ++g) {
        const unsigned m0 = dn2(v[4 * g]);
        const unsigned m1 = dn2(v[(4 * g) ^ 25]);
        const unsigned m2 = dn2(v[(4 * g) ^ 3]);
        const unsigned m3 = dn2(v[(4 * g) ^ 26]);
        const bool rev = ((P ^ (__popc(g) & 1)) != 0);
        const uint4 o = make_uint4(rev ? m3 : m0, rev ? m2 : m1, rev ? m1 : m2, rev ? m0 : m3);
        *(uint4*)(sb + offD[g]) = o;
      }
      __syncthreads();                        // RAW for next layer's pass-A read
    }
  }

  // ---- measurement in D-ownership (final CNOT folded via GF(2) linearity):
  // reg-WHT over j = (bit0, bit1, bit11, bit12, bit13); needed Walsh masks
  // {15,24,28,30,31}; lane/wave signs are Walsh functions of t (amp bits 2..10).
  {
    float p[32];
#pragma unroll
    for (int j = 0; j < 32; ++j) p[j] = v[j].x * v[j].x + v[j].y * v[j].y;
#pragma unroll
    for (int st = 0; st < 5; ++st) {
      const int h = 1 << st;
#pragma unroll
      for (int j = 0; j < 32; ++j) {
        if (!(j & h)) {
          const float u = p[j], w = p[j | h];
          p[j] = u + w;
          p[j | h] = u - w;
        }
      }
    }
    float w28 = p[28], w30 = p[30], w31 = p[31], w15 = p[15], w24 = p[24];
    const int lane = t & 63;
#pragma unroll
    for (int m = 0; m < 6; ++m) {
      const int h = 1 << m;
      const bool hi = (lane & h) != 0;
      float u;
      u = __shfl_xor(w28, h, 64); w28 = hi ? (u - w28) : (u + w28);
      u = __shfl_xor(w30, h, 64); w30 = hi ? (u - w30) : (u + w30);
      u = __shfl_xor(w31, h, 64); w31 = hi ? (u - w31) : (u + w31);
      u = __shfl_xor(w15, h, 64); w15 = hi ? (u - w15) : (u + w15);
      u = __shfl_xor(w24, h, 64); w24 = u + w24;     // plain sum: only lane 0 used
    }
    const int w = t >> 6;
    const float swv = (__popc(w) & 1) ? -1.0f : 1.0f;
    if (lane == 0) {
      red[w][1] = w24;                                   // q1: +
      red[w][2] = w28;                                   // q2: +
      red[w][3] = ((w >> 2) & 1) ? -w28 : w28;           // q3: (-1)^t10
      red[w][4] = (((w >> 1) ^ (w >> 2)) & 1) ? -w28 : w28;  // q4: t9^t10
      red[w][5] = swv * w28;                             // q5: t8^t9^t10
    } else if (lane == 32) { red[w][6]  = swv * w28; }   // q6:  lane mask 0x20
    else if (lane == 48)   { red[w][7]  = swv * w28; }   // q7:  0x30
    else if (lane == 56)   { red[w][8]  = swv * w28; }   // q8:  0x38
    else if (lane == 60)   { red[w][9]  = swv * w28; }   // q9:  0x3C
    else if (lane == 62)   { red[w][10] = swv * w28; }   // q10: 0x3E
    else if (lane == 63)   { red[w][11] = swv * w28;     // q11: 0x3F
                             red[w][12] = swv * w30;     // q12
                             red[w][13] = swv * w31;     // q13
                             red[w][0]  = swv * w15; }   // q0
    __syncthreads();
    if (t < NQ) {
      float sq = 0.0f;
#pragma unroll
      for (int ww = 0; ww < 8; ++ww) sq += red[ww][t];
      out[b * NQ + t] = sq;
    }
  }
}

extern "C" void kernel_launch(void* const* d_in, const int* in_sizes, int n_in,
                              void* d_out, int out_size, void* d_ws, size_t ws_size,
                              hipStream_t stream) {
  const float* x      = (const float*)d_in[0];
  const float* params = (const float*)d_in[1];
  float* out          = (float*)d_out;
  qsim_kernel<<<BATCH, BLK, 0, stream>>>(x, params, out);
}

// Round 10
// 206.208 us; speedup vs baseline: 1.2741x; 1.1374x over previous
//
#include <hip/hip_runtime.h>
#include <hip/hip_fp16.h>

#define NQ     14
#define NL     4
#define BATCH  2048
#define DIM    16384
#define BLK    512
#define NCH    (DIM / 4)            // 4096 logical uint4 chunks (4 amps each, fp16)
#define PCH    (NCH + NCH / 8)      // 4608 physical chunks (pad c + c>>3)

using f2 = __attribute__((ext_vector_type(2))) float;

__device__ __forceinline__ f2 swapf2(f2 v) { return __builtin_shufflevector(v, v, 1, 0); }
__device__ __forceinline__ f2 ff2(float a, float b) { f2 r; r.x = a; r.y = b; return r; }

// fp16 pack/unpack (RN: RTZ's systematic shrink would bias Z)
__device__ __forceinline__ f2 up2(unsigned u) {
  const __half2 h = __builtin_bit_cast(__half2, u);
  return ff2(__low2float(h), __high2float(h));
}
__device__ __forceinline__ unsigned pkpack(float a, float b) {
  return __builtin_bit_cast(unsigned, __floats2half2_rn(a, b));
}
__device__ __forceinline__ unsigned dn2(f2 v) { return pkpack(v.x, v.y); }
__device__ __forceinline__ unsigned sw16(unsigned u) { return __builtin_amdgcn_alignbit(u, u, 16); }

// ---- Shear-form RX rotation (3 FMAs per 2D plane, global sign pre-dropped).
// SoA planes: vx[k]=(x_{2k},x_{2k+1}), vy[k]=(y_{2k},y_{2k+1}).
// Amp-pair (j, j|B) splits into 2D rotations (x_j, y_{j|B}) and (x_{j|B}, y_j),
// each: u = x + t*y ; w = y - s*u ; x' = u + t*w ; y' = w.   Sn = (-s,-s), T = (t,t).
template <int K>  // K = B>>1 for amp-bit B >= 1
__device__ __forceinline__ void rot_k(f2* vx, f2* vy, f2 Sn, f2 T) {
#pragma unroll
  for (int k = 0; k < 16; ++k) {
    if (!(k & K)) {
      const int k1 = k | K;
      const f2 u  = __builtin_elementwise_fma(T, vy[k1], vx[k]);
      const f2 w  = __builtin_elementwise_fma(Sn, u, vy[k1]);
      vx[k]  = __builtin_elementwise_fma(T, w, u);
      vy[k1] = w;
      const f2 u2 = __builtin_elementwise_fma(T, vy[k], vx[k1]);
      const f2 w2 = __builtin_elementwise_fma(Sn, u2, vy[k]);
      vx[k1] = __builtin_elementwise_fma(T, w2, u2);
      vy[k]  = w2;
    }
  }
}
// amp-bit 0 (q13): planes pair within a register -> one swap in, one out.
__device__ __forceinline__ void rot0(f2* vx, f2* vy, f2 Sn, f2 T) {
#pragma unroll
  for (int k = 0; k < 16; ++k) {
    const f2 sy = swapf2(vy[k]);
    const f2 u  = __builtin_elementwise_fma(T, sy, vx[k]);
    const f2 w  = __builtin_elementwise_fma(Sn, u, sy);
    vx[k] = __builtin_elementwise_fma(T, w, u);
    vy[k] = swapf2(w);
  }
}

__global__ __launch_bounds__(BLK)
__attribute__((amdgpu_waves_per_eu(4, 4)))   // VGPR cap 128; exactly 2 blocks/CU
void qsim_kernel(const float* __restrict__ x,
                 const float* __restrict__ params,
                 float* __restrict__ out) {
  __shared__ uint4 lds[PCH];                  // 73728 B state, fp16 SoA chunks, padded
  __shared__ float exc[NQ], exs[NQ];
  __shared__ float gs[NL * NQ], gt[NL * NQ];  // shear gate constants s=sin(phi'), t=tan(phi'/2)
  __shared__ float red[8][16];
  char* const sb = (char*)lds;

  const int b = blockIdx.x;
  const int t = threadIdx.x;

  if (t < NQ) { const float xv = x[b * NQ + t]; exc[t] = cosf(0.5f * xv); exs[t] = sinf(0.5f * xv); }
  if (t < NL * NQ) {
    float ph = 0.5f * params[t];              // phi in [0, pi]
    if (ph > 1.5707964f) ph -= 3.14159265f;   // range-reduce; global -1 dropped
    gs[t] = sinf(ph); gt[t] = tanf(0.5f * ph);
  }
  __syncthreads();

  f2 vx[16], vy[16];

  // ---- per-thread bases (phys chunk = c + (c>>3); layer-invariant)
  char* const pA = sb + 16 * (9 * t);
  char* const pB = sb + 16 * (t & 7) + 1152 * (t >> 3);
  char* const pC = sb + 16 * ((t & 63) + ((t >> 3) & 7) + 576 * (t >> 6));
  char* const pD = sb + 16 * (t + (t >> 3));

  // D CNOT-fold target chunks: MA0 = image of amp bits 2..10 (=t) under ring map
  int MA0 = 0;
  {
    const int Me[9] = {0x2007, 0x200F, 0x201F, 0x203F, 0x207F, 0x20FF, 0x21FF, 0x23FF, 0x27FF};
#pragma unroll
    for (int i = 0; i < 9; ++i) if ((t >> i) & 1) MA0 ^= Me[i];
  }
  int offD[8];
#pragma unroll
  for (int g = 0; g < 8; ++g) {
    const int Mrep = ((g & 1) ? 0x2FFF : 0) ^ ((g & 2) ? 0x3FFF : 0) ^ ((g & 4) ? 0x1FFF : 0);
    const int cT = (MA0 ^ Mrep) >> 2;
    offD[g] = 16 * (cT + (cT >> 3));
  }
  const int P = __popc(t) & 1;

  // ---- embedding in pass-A ownership: amp a = 32t + 4i + l; amp bit p <-> qubit 13-p
  {
    float pb = 1.0f;
#pragma unroll
    for (int p = 0; p < 9; ++p) pb *= ((t >> p) & 1) ? exs[8 - p] : exc[8 - p];
    const int pct = __popc(t);
#pragma unroll
    for (int i = 0; i < 8; ++i) {
      const float fc = ((i & 1) ? exs[11] : exc[11]) * ((i & 2) ? exs[10] : exc[10]) *
                       ((i & 4) ? exs[9] : exc[9]);
      float xv[4], yv[4];
#pragma unroll
      for (int l = 0; l < 4; ++l) {
        const float fl = ((l & 1) ? exs[13] : exc[13]) * ((l & 2) ? exs[12] : exc[12]);
        const float f = pb * fc * fl;
        const int pc = (pct + __popc(i) + __popc(l)) & 3;
        xv[l] = (pc == 0) ? f : ((pc == 2) ? -f : 0.0f);
        yv[l] = (pc == 1) ? -f : ((pc == 3) ? f : 0.0f);
      }
      vx[2 * i] = ff2(xv[0], xv[1]); vy[2 * i] = ff2(yv[0], yv[1]);
      vx[2 * i + 1] = ff2(xv[2], xv[3]); vy[2 * i + 1] = ff2(yv[2], yv[3]);
    }
  }

#pragma unroll
  for (int layer = 0; layer < NL; ++layer) {
    const float* ls = gs + layer * NQ;
    const float* lt = gt + layer * NQ;
    f2 Sn, T;
#define MKST(qi) { const float s_ = ls[qi], t_ = lt[qi]; Sn = ff2(-s_, -s_); T = ff2(t_, t_); }

    // ---- pass A: amps 32t+j; rotate q13..q9 (amp bits 0..4)
    if (layer > 0) {
#pragma unroll
      for (int i = 0; i < 8; ++i) {
        const uint4 u = *(const uint4*)(pA + 16 * i);
        vx[2 * i] = up2(u.x); vy[2 * i] = up2(u.y);
        vx[2 * i + 1] = up2(u.z); vy[2 * i + 1] = up2(u.w);
      }
    }
    MKST(13); rot0(vx, vy, Sn, T);
    MKST(12); rot_k<1>(vx, vy, Sn, T);
    MKST(11); rot_k<2>(vx, vy, Sn, T);
    MKST(10); rot_k<4>(vx, vy, Sn, T);
    MKST(9);  rot_k<8>(vx, vy, Sn, T);
#pragma unroll
    for (int i = 0; i < 8; ++i)
      *(uint4*)(pA + 16 * i) = make_uint4(dn2(vx[2 * i]), dn2(vy[2 * i]),
                                          dn2(vx[2 * i + 1]), dn2(vy[2 * i + 1]));
    __builtin_amdgcn_wave_barrier();          // A->B exchange is wave-private

    // ---- pass B: free {0,1,5,6,7}; rotate q8,q7,q6
#pragma unroll
    for (int m = 0; m < 8; ++m) {
      const uint4 u = *(const uint4*)(pB + 144 * m);
      vx[2 * m] = up2(u.x); vy[2 * m] = up2(u.y);
      vx[2 * m + 1] = up2(u.z); vy[2 * m + 1] = up2(u.w);
    }
    MKST(8); rot_k<2>(vx, vy, Sn, T);
    MKST(7); rot_k<4>(vx, vy, Sn, T);
    MKST(6); rot_k<8>(vx, vy, Sn, T);
#pragma unroll
    for (int m = 0; m < 8; ++m)
      *(uint4*)(pB + 144 * m) = make_uint4(dn2(vx[2 * m]), dn2(vy[2 * m]),
                                           dn2(vx[2 * m + 1]), dn2(vy[2 * m + 1]));
    __builtin_amdgcn_wave_barrier();          // B->C exchange is wave-private

    // ---- pass C: free {0,1,8,9,10}; rotate q5,q4,q3
#pragma unroll
    for (int m = 0; m < 8; ++m) {
      const uint4 u = *(const uint4*)(pC + 1152 * m);
      vx[2 * m] = up2(u.x); vy[2 * m] = up2(u.y);
      vx[2 * m + 1] = up2(u.z); vy[2 * m + 1] = up2(u.w);
    }
    MKST(5); rot_k<2>(vx, vy, Sn, T);
    MKST(4); rot_k<4>(vx, vy, Sn, T);
    MKST(3); rot_k<8>(vx, vy, Sn, T);
#pragma unroll
    for (int m = 0; m < 8; ++m)
      *(uint4*)(pC + 1152 * m) = make_uint4(dn2(vx[2 * m]), dn2(vy[2 * m]),
                                            dn2(vx[2 * m + 1]), dn2(vy[2 * m + 1]));
    __syncthreads();                          // C->D repartition crosses waves

    // ---- pass D: free {0,1,11,12,13}; rotate q2,q1,q0
#pragma unroll
    for (int m = 0; m < 8; ++m) {
      const uint4 u = *(const uint4*)(pD + 9216 * m);
      vx[2 * m] = up2(u.x); vy[2 * m] = up2(u.y);
      vx[2 * m + 1] = up2(u.z); vy[2 * m + 1] = up2(u.w);
    }
    if (layer < NL - 1) __syncthreads();      // WAR: all D reads done before CNOT writes
    MKST(2); rot_k<2>(vx, vy, Sn, T);
    MKST(1); rot_k<4>(vx, vy, Sn, T);
    MKST(0); rot_k<8>(vx, vy, Sn, T);
#undef MKST

    if (layer < NL - 1) {
      // CNOT ring folded into full-chunk writes. Group g: member regs
      // {4g, 4g^25, 4g^3, 4g^26} -> slots {0,1,2,3} (rev=0) or {3,2,1,0} (rev=1).
#pragma unroll
      for (int g = 0; g < 8; ++g) {
        const int k0 = 2 * g;
        const unsigned w0 = pkpack(vx[k0].x,      vx[k0 ^ 12].y);
        const unsigned w1 = pkpack(vy[k0].x,      vy[k0 ^ 12].y);
        const unsigned w2 = pkpack(vx[k0 ^ 1].y,  vx[k0 ^ 13].x);
        const unsigned w3 = pkpack(vy[k0 ^ 1].y,  vy[k0 ^ 13].x);
        const bool rev = ((P ^ (__popc(g) & 1)) != 0);
        const uint4 o = make_uint4(rev ? sw16(w2) : w0, rev ? sw16(w3) : w1,
                                   rev ? sw16(w0) : w2, rev ? sw16(w1) : w3);
        *(uint4*)(sb + offD[g]) = o;
      }
      __syncthreads();                        // RAW for next layer's pass-A read
    }
  }

  // ---- measurement (final CNOT folded via GF(2) linearity).
  // pp[k]=(p_{2k},p_{2k+1}); WHT over k-bits (j bits 1..4) packed, then bit0 via .x/.y.
  {
    f2 pp[16];
#pragma unroll
    for (int k = 0; k < 16; ++k)
      pp[k] = __builtin_elementwise_fma(vx[k], vx[k], vy[k] * vy[k]);
#pragma unroll
    for (int st = 0; st < 4; ++st) {
      const int h = 1 << st;
#pragma unroll
      for (int k = 0; k < 16; ++k) {
        if (!(k & h)) {
          const f2 u = pp[k], w = pp[k | h];
          pp[k] = u + w;
          pp[k | h] = u - w;
        }
      }
    }
    float w24 = pp[12].x + pp[12].y;
    float w28 = pp[14].x + pp[14].y;
    float w30 = pp[15].x + pp[15].y;
    float w31 = pp[15].x - pp[15].y;
    float w15 = pp[7].x - pp[7].y;

    const int lane = t & 63;
#pragma unroll
    for (int m = 0; m < 6; ++m) {
      const int h = 1 << m;
      const bool hi = (lane & h) != 0;
      float u;
      u = __shfl_xor(w28, h, 64); w28 = hi ? (u - w28) : (u + w28);
      u = __shfl_xor(w30, h, 64); w30 = hi ? (u - w30) : (u + w30);
      u = __shfl_xor(w31, h, 64); w31 = hi ? (u - w31) : (u + w31);
      u = __shfl_xor(w15, h, 64); w15 = hi ? (u - w15) : (u + w15);
      u = __shfl_xor(w24, h, 64); w24 = u + w24;     // plain sum: only lane 0 used
    }
    const int w = t >> 6;
    const float swv = (__popc(w) & 1) ? -1.0f : 1.0f;
    if (lane == 0) {
      red[w][1] = w24;                                   // q1: +
      red[w][2] = w28;                                   // q2: +
      red[w][3] = ((w >> 2) & 1) ? -w28 : w28;           // q3: (-1)^t10
      red[w][4] = (((w >> 1) ^ (w >> 2)) & 1) ? -w28 : w28;  // q4: t9^t10
      red[w][5] = swv * w28;                             // q5: t8^t9^t10
    } else if (lane == 32) { red[w][6]  = swv * w28; }   // q6:  lane mask 0x20
    else if (lane == 48)   { red[w][7]  = swv * w28; }   // q7:  0x30
    else if (lane == 56)   { red[w][8]  = swv * w28; }   // q8:  0x38
    else if (lane == 60)   { red[w][9]  = swv * w28; }   // q9:  0x3C
    else if (lane == 62)   { red[w][10] = swv * w28; }   // q10: 0x3E
    else if (lane == 63)   { red[w][11] = swv * w28;     // q11: 0x3F
                             red[w][12] = swv * w30;     // q12
                             red[w][13] = swv * w31;     // q13
                             red[w][0]  = swv * w15; }   // q0
    __syncthreads();
    if (t < NQ) {
      float sq = 0.0f;
#pragma unroll
      for (int ww = 0; ww < 8; ++ww) sq += red[ww][t];
      out[b * NQ + t] = sq;
    }
  }
}

extern "C" void kernel_launch(void* const* d_in, const int* in_sizes, int n_in,
                              void* d_out, int out_size, void* d_ws, size_t ws_size,
                              hipStream_t stream) {
  const float* x      = (const float*)d_in[0];
  const float* params = (const float*)d_in[1];
  float* out          = (float*)d_out;
  qsim_kernel<<<BATCH, BLK, 0, stream>>>(x, params, out);
}

// Round 11
// 183.201 us; speedup vs baseline: 1.4340x; 1.1256x over previous
//
#include <hip/hip_runtime.h>
#include <hip/hip_fp16.h>

#define NQ     14
#define NL     4
#define BATCH  2048
#define DIM    16384
#define BLK    512
#define NCH    (DIM / 4)            // 4096 logical uint4 chunks (4 amps, fp16 SoA)
#define PCH    (NCH + NCH / 8)      // 4608 physical chunks (pad c + c>>3)

using f2 = __attribute__((ext_vector_type(2))) float;
__device__ __forceinline__ f2 ff2(float a, float b) { f2 r; r.x = a; r.y = b; return r; }

__device__ __forceinline__ unsigned h2u(__half2 h) { return __builtin_bit_cast(unsigned, h); }
__device__ __forceinline__ __half2 u2h(unsigned u) { return __builtin_bit_cast(__half2, u); }
__device__ __forceinline__ unsigned sw16(unsigned u) { return __builtin_amdgcn_alignbit(u, u, 16); }

// ---- Shear RX in packed fp16 (3 pk-FMA per 2D plane pair; swap-free for amp-bit>=1).
// X[k]=(x_{2k},x_{2k+1}), Y[k]=(y_{2k},y_{2k+1}).  T=(t,t), Sn=(-s,-s),
// t = tan(phi/2) rounded to fp16, s derived from rounded t (map stays a rotation).
template <int K>  // K = amp-bit >> 1, for amp-bit >= 1
__device__ __forceinline__ void rot_k(__half2* X, __half2* Y, __half2 T, __half2 Sn) {
#pragma unroll
  for (int k = 0; k < 16; ++k) {
    if (!(k & K)) {
      const int k1 = k | K;
      const __half2 u1 = __hfma2(T, Y[k1], X[k]);
      const __half2 w1 = __hfma2(Sn, u1, Y[k1]);
      X[k]  = __hfma2(T, w1, u1);
      Y[k1] = w1;
      const __half2 u2 = __hfma2(T, Y[k], X[k1]);
      const __half2 w2 = __hfma2(Sn, u2, Y[k]);
      X[k1] = __hfma2(T, w2, u2);
      Y[k]  = w2;
    }
  }
}
// amp-bit 0 (q13): partner inside the packed register -> half-swaps (op_sel-foldable)
__device__ __forceinline__ void rot0(__half2* X, __half2* Y, __half2 T, __half2 Sn) {
#pragma unroll
  for (int k = 0; k < 16; ++k) {
    const __half2 sy = __lowhigh2highlow(Y[k]);
    const __half2 u = __hfma2(T, sy, X[k]);
    const __half2 w = __hfma2(Sn, u, sy);
    X[k] = __hfma2(T, w, u);
    Y[k] = __lowhigh2highlow(w);
  }
}

__global__ __launch_bounds__(BLK)
__attribute__((amdgpu_waves_per_eu(4, 4)))   // VGPR cap 128; exactly 2 blocks/CU
void qsim_kernel(const float* __restrict__ x,
                 const float* __restrict__ params,
                 float* __restrict__ out) {
  __shared__ uint4 lds[PCH];                  // 73728 B state, fp16 SoA chunks, padded
  __shared__ float exc[NQ], exs[NQ];
  __shared__ uint2 gTS[NL * NQ];              // per-gate packed (T=(t,t), Sn=(-s,-s))
  __shared__ float red[8][16];
  char* const sb = (char*)lds;

  const int b = blockIdx.x;
  const int t = threadIdx.x;

  if (t < NQ) { const float xv = x[b * NQ + t]; exc[t] = cosf(0.5f * xv); exs[t] = sinf(0.5f * xv); }
  if (t < NL * NQ) {
    float ph = 0.5f * params[t];              // phi in [0, pi]
    if (ph > 1.5707964f) ph -= 3.14159265f;   // range-reduce; global -1 is pure phase
    const float tf = tanf(0.5f * ph);
    const __half th = __float2half_rn(tf);
    const float thf = __half2float(th);
    const float sf = 2.0f * thf / (1.0f + thf * thf);  // consistent with rounded t
    gTS[t] = make_uint2(h2u(__half2half2(th)), h2u(__float2half2_rn(-sf)));
  }
  __syncthreads();

  __half2 X[16], Y[16];                       // 32 amps: SoA x/y planes, fp16 packed

  // ---- per-thread bases (phys chunk = c + (c>>3); layer-invariant)
  char* const pA = sb + 16 * (9 * t);
  char* const pB = sb + 16 * (t & 7) + 1152 * (t >> 3);
  char* const pC = sb + 16 * ((t & 63) + ((t >> 3) & 7) + 576 * (t >> 6));
  char* const pD = sb + 16 * (t + (t >> 3));

  // D CNOT-fold target chunks: MA0 = image of amp bits 2..10 (=t) under ring map
  int MA0 = 0;
  {
    const int Me[9] = {0x2007, 0x200F, 0x201F, 0x203F, 0x207F, 0x20FF, 0x21FF, 0x23FF, 0x27FF};
#pragma unroll
    for (int i = 0; i < 9; ++i) if ((t >> i) & 1) MA0 ^= Me[i];
  }
  int offD[8];
#pragma unroll
  for (int g = 0; g < 8; ++g) {
    const int Mrep = ((g & 1) ? 0x2FFF : 0) ^ ((g & 2) ? 0x3FFF : 0) ^ ((g & 4) ? 0x1FFF : 0);
    const int cT = (MA0 ^ Mrep) >> 2;
    offD[g] = 16 * (cT + (cT >> 3));
  }
  const int P = __popc(t) & 1;

  // ---- embedding in pass-A ownership: amp a = 32t + 4i + l (fp32, packed once)
  {
    float pb = 1.0f;
#pragma unroll
    for (int p = 0; p < 9; ++p) pb *= ((t >> p) & 1) ? exs[8 - p] : exc[8 - p];
    const int pct = __popc(t);
#pragma unroll
    for (int i = 0; i < 8; ++i) {
      const float fc = ((i & 1) ? exs[11] : exc[11]) * ((i & 2) ? exs[10] : exc[10]) *
                       ((i & 4) ? exs[9] : exc[9]);
      float xv[4], yv[4];
#pragma unroll
      for (int l = 0; l < 4; ++l) {
        const float fl = ((l & 1) ? exs[13] : exc[13]) * ((l & 2) ? exs[12] : exc[12]);
        const float f = pb * fc * fl;
        const int pc = (pct + __popc(i) + __popc(l)) & 3;
        xv[l] = (pc == 0) ? f : ((pc == 2) ? -f : 0.0f);
        yv[l] = (pc == 1) ? -f : ((pc == 3) ? f : 0.0f);
      }
      X[2 * i]     = __floats2half2_rn(xv[0], xv[1]);
      X[2 * i + 1] = __floats2half2_rn(xv[2], xv[3]);
      Y[2 * i]     = __floats2half2_rn(yv[0], yv[1]);
      Y[2 * i + 1] = __floats2half2_rn(yv[2], yv[3]);
    }
  }

#pragma unroll
  for (int layer = 0; layer < NL; ++layer) {
    __half2 T, Sn;
#define MKST(qi) { const uint2 g_ = gTS[layer * NQ + (qi)]; T = u2h(g_.x); Sn = u2h(g_.y); }

    // ---- pass A: amps 32t+j; rotate q13..q9 (amp bits 0..4)
    if (layer > 0) {
#pragma unroll
      for (int i = 0; i < 8; ++i) {
        const uint4 u = *(const uint4*)(pA + 16 * i);
        X[2 * i] = u2h(u.x); Y[2 * i] = u2h(u.y);
        X[2 * i + 1] = u2h(u.z); Y[2 * i + 1] = u2h(u.w);
      }
    }
    MKST(13); rot0(X, Y, T, Sn);
    MKST(12); rot_k<1>(X, Y, T, Sn);
    MKST(11); rot_k<2>(X, Y, T, Sn);
    MKST(10); rot_k<4>(X, Y, T, Sn);
    MKST(9);  rot_k<8>(X, Y, T, Sn);
#pragma unroll
    for (int i = 0; i < 8; ++i)
      *(uint4*)(pA + 16 * i) = make_uint4(h2u(X[2 * i]), h2u(Y[2 * i]),
                                          h2u(X[2 * i + 1]), h2u(Y[2 * i + 1]));
    __builtin_amdgcn_wave_barrier();          // A->B exchange is wave-private

    // ---- pass B: free {0,1,5,6,7}; rotate q8,q7,q6
#pragma unroll
    for (int m = 0; m < 8; ++m) {
      const uint4 u = *(const uint4*)(pB + 144 * m);
      X[2 * m] = u2h(u.x); Y[2 * m] = u2h(u.y);
      X[2 * m + 1] = u2h(u.z); Y[2 * m + 1] = u2h(u.w);
    }
    MKST(8); rot_k<2>(X, Y, T, Sn);
    MKST(7); rot_k<4>(X, Y, T, Sn);
    MKST(6); rot_k<8>(X, Y, T, Sn);
#pragma unroll
    for (int m = 0; m < 8; ++m)
      *(uint4*)(pB + 144 * m) = make_uint4(h2u(X[2 * m]), h2u(Y[2 * m]),
                                           h2u(X[2 * m + 1]), h2u(Y[2 * m + 1]));
    __builtin_amdgcn_wave_barrier();          // B->C exchange is wave-private

    // ---- pass C: free {0,1,8,9,10}; rotate q5,q4,q3
#pragma unroll
    for (int m = 0; m < 8; ++m) {
      const uint4 u = *(const uint4*)(pC + 1152 * m);
      X[2 * m] = u2h(u.x); Y[2 * m] = u2h(u.y);
      X[2 * m + 1] = u2h(u.z); Y[2 * m + 1] = u2h(u.w);
    }
    MKST(5); rot_k<2>(X, Y, T, Sn);
    MKST(4); rot_k<4>(X, Y, T, Sn);
    MKST(3); rot_k<8>(X, Y, T, Sn);
#pragma unroll
    for (int m = 0; m < 8; ++m)
      *(uint4*)(pC + 1152 * m) = make_uint4(h2u(X[2 * m]), h2u(Y[2 * m]),
                                            h2u(X[2 * m + 1]), h2u(Y[2 * m + 1]));
    __syncthreads();                          // C->D repartition crosses waves

    // ---- pass D: free {0,1,11,12,13}; rotate q2,q1,q0
#pragma unroll
    for (int m = 0; m < 8; ++m) {
      const uint4 u = *(const uint4*)(pD + 9216 * m);
      X[2 * m] = u2h(u.x); Y[2 * m] = u2h(u.y);
      X[2 * m + 1] = u2h(u.z); Y[2 * m + 1] = u2h(u.w);
    }
    if (layer < NL - 1) __syncthreads();      // WAR: all D reads done before CNOT writes
    MKST(2); rot_k<2>(X, Y, T, Sn);
    MKST(1); rot_k<4>(X, Y, T, Sn);
    MKST(0); rot_k<8>(X, Y, T, Sn);
#undef MKST

    if (layer < NL - 1) {
      // CNOT ring folded into full-chunk writes; half-mixes are single v_perm_b32.
#pragma unroll
      for (int g = 0; g < 8; ++g) {
        const int k0 = 2 * g;
        const unsigned w0 = __builtin_amdgcn_perm(h2u(X[k0 ^ 12]), h2u(X[k0]), 0x07060100u);
        const unsigned w1 = __builtin_amdgcn_perm(h2u(Y[k0 ^ 12]), h2u(Y[k0]), 0x07060100u);
        const unsigned w2 = __builtin_amdgcn_perm(h2u(X[k0 ^ 13]), h2u(X[k0 ^ 1]), 0x05040302u);
        const unsigned w3 = __builtin_amdgcn_perm(h2u(Y[k0 ^ 13]), h2u(Y[k0 ^ 1]), 0x05040302u);
        const bool rev = ((P ^ (__popc(g) & 1)) != 0);
        const uint4 o = make_uint4(rev ? sw16(w2) : w0, rev ? sw16(w3) : w1,
                                   rev ? sw16(w0) : w2, rev ? sw16(w1) : w3);
        *(uint4*)(sb + offD[g]) = o;
      }
      __syncthreads();                        // RAW for next layer's pass-A read
    }
  }

  // ---- measurement (final CNOT folded via GF(2) linearity); probs in fp32.
  {
    f2 pp[16];
#pragma unroll
    for (int k = 0; k < 16; ++k) {
      const float xl = __low2float(X[k]), xh = __high2float(X[k]);
      const float yl = __low2float(Y[k]), yh = __high2float(Y[k]);
      pp[k] = ff2(fmaf(xl, xl, yl * yl), fmaf(xh, xh, yh * yh));
    }
#pragma unroll
    for (int st = 0; st < 4; ++st) {
      const int h = 1 << st;
#pragma unroll
      for (int k = 0; k < 16; ++k) {
        if (!(k & h)) {
          const f2 u = pp[k], w = pp[k | h];
          pp[k] = u + w;
          pp[k | h] = u - w;
        }
      }
    }
    float w24 = pp[12].x + pp[12].y;
    float w28 = pp[14].x + pp[14].y;
    float w30 = pp[15].x + pp[15].y;
    float w31 = pp[15].x - pp[15].y;
    float w15 = pp[7].x - pp[7].y;

    const int lane = t & 63;
#pragma unroll
    for (int m = 0; m < 6; ++m) {
      const int h = 1 << m;
      const bool hi = (lane & h) != 0;
      float u;
      u = __shfl_xor(w28, h, 64); w28 = hi ? (u - w28) : (u + w28);
      u = __shfl_xor(w30, h, 64); w30 = hi ? (u - w30) : (u + w30);
      u = __shfl_xor(w31, h, 64); w31 = hi ? (u - w31) : (u + w31);
      u = __shfl_xor(w15, h, 64); w15 = hi ? (u - w15) : (u + w15);
      u = __shfl_xor(w24, h, 64); w24 = u + w24;     // plain sum: only lane 0 used
    }
    const int w = t >> 6;
    const float swv = (__popc(w) & 1) ? -1.0f : 1.0f;
    if (lane == 0) {
      red[w][1] = w24;                                   // q1: +
      red[w][2] = w28;                                   // q2: +
      red[w][3] = ((w >> 2) & 1) ? -w28 : w28;           // q3: (-1)^t10
      red[w][4] = (((w >> 1) ^ (w >> 2)) & 1) ? -w28 : w28;  // q4: t9^t10
      red[w][5] = swv * w28;                             // q5: t8^t9^t10
    } else if (lane == 32) { red[w][6]  = swv * w28; }   // q6:  lane mask 0x20
    else if (lane == 48)   { red[w][7]  = swv * w28; }   // q7:  0x30
    else if (lane == 56)   { red[w][8]  = swv * w28; }   // q8:  0x38
    else if (lane == 60)   { red[w][9]  = swv * w28; }   // q9:  0x3C
    else if (lane == 62)   { red[w][10] = swv * w28; }   // q10: 0x3E
    else if (lane == 63)   { red[w][11] = swv * w28;     // q11: 0x3F
                             red[w][12] = swv * w30;     // q12
                             red[w][13] = swv * w31;     // q13
                             red[w][0]  = swv * w15; }   // q0
    __syncthreads();
    if (t < NQ) {
      float sq = 0.0f;
#pragma unroll
      for (int ww = 0; ww < 8; ++ww) sq += red[ww][t];
      out[b * NQ + t] = sq;
    }
  }
}

extern "C" void kernel_launch(void* const* d_in, const int* in_sizes, int n_in,
                              void* d_out, int out_size, void* d_ws, size_t ws_size,
                              hipStream_t stream) {
  const float* x      = (const float*)d_in[0];
  const float* params = (const float*)d_in[1];
  float* out          = (float*)d_out;
  qsim_kernel<<<BATCH, BLK, 0, stream>>>(x, params, out);
}